// Round 6
// baseline (1801.890 us; speedup 1.0000x reference)
//
#include <hip/hip_runtime.h>

// SSIM3D loss, 64 x 64^3 f32 volumes, separable 7-tap gaussian, edge clamp.
// lanes = z (coalesced). z-conv via per-lane clamped VMEM tap loads (L1-hit).
// Packed f32x2 math: (img1,img2) pairs and (e11,e22)/(m1,m2) field pairs ->
// v_pk_fma_f32. y streamed in 7-deep register windows, rotation via unroll 7.
// x-conv via conflict-free SoA LDS (b64 lane-consecutive reads).

typedef float f32x2 __attribute__((ext_vector_type(2)));

#define G0 0.03663285f
#define G1 0.11128074f
#define G2 0.21674532f
#define G3 0.27068219f
#define SC1 1e-4f
#define SC2 9e-4f

__global__ void zero_acc_kernel(double* acc) { if (threadIdx.x == 0) *acc = 0.0; }

__global__ void finalize_kernel(const double* __restrict__ acc, float* __restrict__ out) {
    if (threadIdx.x == 0) out[0] = (float)(*acc * (1.0 / 16777216.0));
}

__launch_bounds__(256, 4)
__global__ void ssim3d_kernel(const float* __restrict__ preds,
                              const float* __restrict__ trues,
                              double* __restrict__ acc)
{
    const int tid = threadIdx.x;
    const int z   = tid & 63;          // lane = z (contiguous dim)
    const int w   = tid >> 6;          // wave 0..3
    const int v   = blockIdx.x & 63;   // volume; its 16 blocks share an XCD (L2-resident 2MB)
    const int r   = blockIdx.x >> 6;   // 0..15 = tx*2 + h
    const int h   = r & 1;
    const int tx  = r >> 1;
    const int xo  = tx << 3;
    const int oy  = h << 5;            // 32 output y per block

    __shared__ f32x2 s01[2][14][64];   // (mu1, mu2)
    __shared__ f32x2 s23[2][14][64];   // (e11, e22)
    __shared__ float s4 [2][14][64];   // e12
    __shared__ float wsum[4];

    const float* __restrict__ xp = preds + ((size_t)v << 18);
    const float* __restrict__ yp = trues + ((size_t)v << 18);

    // per-lane clamped z-tap offsets (replicate padding), loop-invariant
    int zoff[7];
#pragma unroll
    for (int j = 0; j < 7; ++j) zoff[j] = min(max(z + j - 3, 0), 63);

    // wave-uniform column bases: px = w + 4k covers 0..13 (w>=2,k==3 unused)
    int cbase[4];
#pragma unroll
    for (int k = 0; k < 4; ++k) {
        int px = w + 4*k; if (px > 13) px = 13;
        int gx = min(max(xo - 3 + px, 0), 63);
        cbase[k] = gx << 12;
    }

    f32x2 W01[2][7] = {};              // windows for outputs x = 2w, 2w+1
    f32x2 W23[2][7] = {};
    float W4 [2][7] = {};
    float lsum = 0.f;

#pragma unroll 7
    for (int s = 0; s < 38; ++s) {
        const int par = s & 1;
        const int gy  = min(max(oy - 3 + s, 0), 63);
        const int pb  = gy << 6;

        // ---- z-conv (packed) + SoA store ----
#pragma unroll
        for (int k = 0; k < 4; ++k) if (k < 3 || w < 2) {
            const int cb = __builtin_amdgcn_readfirstlane(cbase[k] + pb);
            const float* pA = xp + cb;
            const float* pB = yp + cb;
            f32x2 t0 = {pA[zoff[0]], pB[zoff[0]]};
            f32x2 t1 = {pA[zoff[1]], pB[zoff[1]]};
            f32x2 t2 = {pA[zoff[2]], pB[zoff[2]]};
            f32x2 t3 = {pA[zoff[3]], pB[zoff[3]]};
            f32x2 t4 = {pA[zoff[4]], pB[zoff[4]]};
            f32x2 t5 = {pA[zoff[5]], pB[zoff[5]]};
            f32x2 t6 = {pA[zoff[6]], pB[zoff[6]]};

            f32x2 mu = G0*(t0+t6) + G1*(t1+t5) + G2*(t2+t4) + G3*t3;
            f32x2 ee = G0*(t0*t0 + t6*t6) + G1*(t1*t1 + t5*t5)
                     + G2*(t2*t2 + t4*t4) + G3*(t3*t3);
            float c0 = t0.x*t0.y, c1 = t1.x*t1.y, c2 = t2.x*t2.y, c3 = t3.x*t3.y,
                  c4 = t4.x*t4.y, c5 = t5.x*t5.y, c6 = t6.x*t6.y;
            float e12 = G0*(c0+c6) + G1*(c1+c5) + G2*(c2+c4) + G3*c3;

            const int col = w + 4*k;
            s01[par][col][z] = mu;
            s23[par][col][z] = ee;
            s4 [par][col][z] = e12;
        }
        __syncthreads();

        // ---- x-conv: 8 shared taps -> outputs 2w, 2w+1 (packed field-pairs) ----
        f32x2 X01[2], X23[2]; float X4[2];
        {
            const int c0i = 2*w;
            f32x2 T0=s01[par][c0i+0][z], T1=s01[par][c0i+1][z], T2=s01[par][c0i+2][z],
                  T3=s01[par][c0i+3][z], T4=s01[par][c0i+4][z], T5=s01[par][c0i+5][z],
                  T6=s01[par][c0i+6][z], T7=s01[par][c0i+7][z];
            X01[0] = G0*(T0+T6) + G1*(T1+T5) + G2*(T2+T4) + G3*T3;
            X01[1] = G0*(T1+T7) + G1*(T2+T6) + G2*(T3+T5) + G3*T4;
            f32x2 U0=s23[par][c0i+0][z], U1=s23[par][c0i+1][z], U2=s23[par][c0i+2][z],
                  U3=s23[par][c0i+3][z], U4=s23[par][c0i+4][z], U5=s23[par][c0i+5][z],
                  U6=s23[par][c0i+6][z], U7=s23[par][c0i+7][z];
            X23[0] = G0*(U0+U6) + G1*(U1+U5) + G2*(U2+U4) + G3*U3;
            X23[1] = G0*(U1+U7) + G1*(U2+U6) + G2*(U3+U5) + G3*U4;
            float V0=s4[par][c0i+0][z], V1=s4[par][c0i+1][z], V2=s4[par][c0i+2][z],
                  V3=s4[par][c0i+3][z], V4=s4[par][c0i+4][z], V5=s4[par][c0i+5][z],
                  V6=s4[par][c0i+6][z], V7=s4[par][c0i+7][z];
            X4[0] = G0*(V0+V6) + G1*(V1+V5) + G2*(V2+V4) + G3*V3;
            X4[1] = G0*(V1+V7) + G1*(V2+V6) + G2*(V3+V5) + G3*V4;
        }

        // ---- rotate windows (renamed by unroll-7), push new plane ----
#pragma unroll
        for (int o = 0; o < 2; ++o) {
#pragma unroll
            for (int i = 0; i < 6; ++i) {
                W01[o][i] = W01[o][i+1];
                W23[o][i] = W23[o][i+1];
                W4 [o][i] = W4 [o][i+1];
            }
            W01[o][6] = X01[o];
            W23[o][6] = X23[o];
            W4 [o][6] = X4[o];
        }

        // ---- emit y = oy + s - 6 ----
        if (s >= 6) {
#pragma unroll
            for (int o = 0; o < 2; ++o) {
                f32x2 F01 = G0*(W01[o][0]+W01[o][6]) + G1*(W01[o][1]+W01[o][5])
                          + G2*(W01[o][2]+W01[o][4]) + G3*W01[o][3];
                f32x2 F23 = G0*(W23[o][0]+W23[o][6]) + G1*(W23[o][1]+W23[o][5])
                          + G2*(W23[o][2]+W23[o][4]) + G3*W23[o][3];
                float F4  = G0*(W4[o][0]+W4[o][6]) + G1*(W4[o][1]+W4[o][5])
                          + G2*(W4[o][2]+W4[o][4]) + G3*W4[o][3];
                float mu1 = F01.x, mu2 = F01.y;
                float m12 = mu1 * mu2;
                f32x2 msq = F01 * F01;            // (m11, m22)
                f32x2 sg  = F23 - msq;            // (s11, s22)
                float num = (2.f*m12 + SC1) * (2.f*(F4 - m12) + SC2);
                float den = (msq.x + msq.y + SC1) * (sg.x + sg.y + SC2) + 1e-12f;
                lsum += 1.f - num * __builtin_amdgcn_rcpf(den);
            }
        }
    }

    // ---- block reduction, one f64 atomic ----
#pragma unroll
    for (int off = 32; off > 0; off >>= 1)
        lsum += __shfl_down(lsum, off);
    if ((tid & 63) == 0) wsum[w] = lsum;
    __syncthreads();
    if (tid == 0)
        atomicAdd(acc, (double)(wsum[0] + wsum[1] + wsum[2] + wsum[3]));
}

extern "C" void kernel_launch(void* const* d_in, const int* in_sizes, int n_in,
                              void* d_out, int out_size, void* d_ws, size_t ws_size,
                              hipStream_t stream) {
    const float* preds = (const float*)d_in[0];
    const float* trues = (const float*)d_in[1];
    float* out = (float*)d_out;
    double* acc = (double*)d_ws;

    hipLaunchKernelGGL(zero_acc_kernel, dim3(1), dim3(64), 0, stream, acc);

    const int nblocks = 64 * 16;   // bid = (tx*2+h)*64 + v
    hipLaunchKernelGGL(ssim3d_kernel, dim3(nblocks), dim3(256), 0, stream,
                       preds, trues, acc);

    hipLaunchKernelGGL(finalize_kernel, dim3(1), dim3(64), 0, stream, acc, out);
}

// Round 7
// 123.766 us; speedup vs baseline: 14.5588x; 14.5588x over previous
//
#include <hip/hip_runtime.h>

// SSIM3D loss, 64 x 64^3 f32 volumes, separable 7-tap gaussian, edge clamp.
// lanes = z (coalesced). z-conv via per-lane clamped VMEM tap loads (L1-hit).
// Packed f32x2 math ((img1,img2) and (mu1,mu2)/(e11,e22) pairs -> v_pk_*).
// y streamed in 7-deep register windows with EXPLICIT compile-time shifts
// (no outer unroll — round-6 lesson: unroll-7 spilled windows to scratch,
// 3 GB scratch traffic, 15x slowdown). x-conv via conflict-free SoA LDS.

typedef float f32x2 __attribute__((ext_vector_type(2)));

#define G0 0.03663285f
#define G1 0.11128074f
#define G2 0.21674532f
#define G3 0.27068219f
#define SC1 1e-4f
#define SC2 9e-4f

__global__ void zero_acc_kernel(double* acc) { if (threadIdx.x == 0) *acc = 0.0; }

__global__ void finalize_kernel(const double* __restrict__ acc, float* __restrict__ out) {
    if (threadIdx.x == 0) out[0] = (float)(*acc * (1.0 / 16777216.0));
}

__launch_bounds__(256, 4)
__global__ void ssim3d_kernel(const float* __restrict__ preds,
                              const float* __restrict__ trues,
                              double* __restrict__ acc)
{
    const int tid = threadIdx.x;
    const int z   = tid & 63;          // lane = z (contiguous dim)
    const int w   = tid >> 6;          // wave 0..3
    const int v   = blockIdx.x & 63;   // volume; its 16 blocks share an XCD
    const int r   = blockIdx.x >> 6;   // 0..15 = tx*2 + h
    const int h   = r & 1;
    const int tx  = r >> 1;
    const int xo  = tx << 3;
    const int oy  = h << 5;            // 32 output y per block

    __shared__ f32x2 s01[2][14][64];   // (mu1, mu2)
    __shared__ f32x2 s23[2][14][64];   // (e11, e22)
    __shared__ float s4 [2][14][64];   // e12
    __shared__ float wsum[4];

    const float* __restrict__ xp = preds + ((size_t)v << 18);
    const float* __restrict__ yp = trues + ((size_t)v << 18);

    // per-lane clamped z-tap offsets (replicate padding), loop-invariant
    int zoff[7];
#pragma unroll
    for (int j = 0; j < 7; ++j) zoff[j] = min(max(z + j - 3, 0), 63);

    // wave-uniform column bases: px = w + 4k covers 0..13 (w>=2,k==3 unused)
    int cbase[4];
#pragma unroll
    for (int k = 0; k < 4; ++k) {
        int px = w + 4*k; if (px > 13) px = 13;
        int gx = min(max(xo - 3 + px, 0), 63);
        cbase[k] = gx << 12;
    }

    f32x2 W01[2][7], W23[2][7];        // windows for outputs x = 2w, 2w+1
    float W4 [2][7];
    float lsum = 0.f;

    for (int s = 0; s < 38; ++s) {
        const int par = s & 1;
        const int gy  = min(max(oy - 3 + s, 0), 63);
        const int pb  = gy << 6;

        // ---- z-conv (packed) + SoA store ----
#pragma unroll
        for (int k = 0; k < 4; ++k) if (k < 3 || w < 2) {
            const int cb = __builtin_amdgcn_readfirstlane(cbase[k] + pb);
            const float* pA = xp + cb;
            const float* pB = yp + cb;
            f32x2 t0 = {pA[zoff[0]], pB[zoff[0]]};
            f32x2 t1 = {pA[zoff[1]], pB[zoff[1]]};
            f32x2 t2 = {pA[zoff[2]], pB[zoff[2]]};
            f32x2 t3 = {pA[zoff[3]], pB[zoff[3]]};
            f32x2 t4 = {pA[zoff[4]], pB[zoff[4]]};
            f32x2 t5 = {pA[zoff[5]], pB[zoff[5]]};
            f32x2 t6 = {pA[zoff[6]], pB[zoff[6]]};

            f32x2 mu = G0*(t0+t6) + G1*(t1+t5) + G2*(t2+t4) + G3*t3;
            f32x2 ee = G0*(t0*t0 + t6*t6) + G1*(t1*t1 + t5*t5)
                     + G2*(t2*t2 + t4*t4) + G3*(t3*t3);
            float c0 = t0.x*t0.y, c1 = t1.x*t1.y, c2 = t2.x*t2.y, c3 = t3.x*t3.y,
                  c4 = t4.x*t4.y, c5 = t5.x*t5.y, c6 = t6.x*t6.y;
            float e12 = G0*(c0+c6) + G1*(c1+c5) + G2*(c2+c4) + G3*c3;

            const int col = w + 4*k;
            s01[par][col][z] = mu;
            s23[par][col][z] = ee;
            s4 [par][col][z] = e12;
        }
        __syncthreads();

        // ---- shift windows (compile-time indices, stays in registers) ----
#pragma unroll
        for (int o = 0; o < 2; ++o) {
#pragma unroll
            for (int i = 0; i < 6; ++i) {
                W01[o][i] = W01[o][i+1];
                W23[o][i] = W23[o][i+1];
                W4 [o][i] = W4 [o][i+1];
            }
        }

        // ---- x-conv: 8 shared taps -> outputs 2w, 2w+1 (packed field-pairs) ----
        {
            const int c0i = 2*w;
            f32x2 T0=s01[par][c0i+0][z], T1=s01[par][c0i+1][z], T2=s01[par][c0i+2][z],
                  T3=s01[par][c0i+3][z], T4=s01[par][c0i+4][z], T5=s01[par][c0i+5][z],
                  T6=s01[par][c0i+6][z], T7=s01[par][c0i+7][z];
            W01[0][6] = G0*(T0+T6) + G1*(T1+T5) + G2*(T2+T4) + G3*T3;
            W01[1][6] = G0*(T1+T7) + G1*(T2+T6) + G2*(T3+T5) + G3*T4;
            f32x2 U0=s23[par][c0i+0][z], U1=s23[par][c0i+1][z], U2=s23[par][c0i+2][z],
                  U3=s23[par][c0i+3][z], U4=s23[par][c0i+4][z], U5=s23[par][c0i+5][z],
                  U6=s23[par][c0i+6][z], U7=s23[par][c0i+7][z];
            W23[0][6] = G0*(U0+U6) + G1*(U1+U5) + G2*(U2+U4) + G3*U3;
            W23[1][6] = G0*(U1+U7) + G1*(U2+U6) + G2*(U3+U5) + G3*U4;
            float V0=s4[par][c0i+0][z], V1=s4[par][c0i+1][z], V2=s4[par][c0i+2][z],
                  V3=s4[par][c0i+3][z], V4=s4[par][c0i+4][z], V5=s4[par][c0i+5][z],
                  V6=s4[par][c0i+6][z], V7=s4[par][c0i+7][z];
            W4[0][6] = G0*(V0+V6) + G1*(V1+V5) + G2*(V2+V4) + G3*V3;
            W4[1][6] = G0*(V1+V7) + G1*(V2+V6) + G2*(V3+V5) + G3*V4;
        }

        // ---- emit y = oy + s - 6 ----
        if (s >= 6) {
#pragma unroll
            for (int o = 0; o < 2; ++o) {
                f32x2 F01 = G0*(W01[o][0]+W01[o][6]) + G1*(W01[o][1]+W01[o][5])
                          + G2*(W01[o][2]+W01[o][4]) + G3*W01[o][3];
                f32x2 F23 = G0*(W23[o][0]+W23[o][6]) + G1*(W23[o][1]+W23[o][5])
                          + G2*(W23[o][2]+W23[o][4]) + G3*W23[o][3];
                float F4  = G0*(W4[o][0]+W4[o][6]) + G1*(W4[o][1]+W4[o][5])
                          + G2*(W4[o][2]+W4[o][4]) + G3*W4[o][3];
                float mu1 = F01.x, mu2 = F01.y;
                float m12 = mu1 * mu2;
                f32x2 msq = F01 * F01;            // (m11, m22)
                f32x2 sg  = F23 - msq;            // (s11, s22)
                float num = (2.f*m12 + SC1) * (2.f*(F4 - m12) + SC2);
                float den = (msq.x + msq.y + SC1) * (sg.x + sg.y + SC2) + 1e-12f;
                lsum += 1.f - num * __builtin_amdgcn_rcpf(den);
            }
        }
    }

    // ---- block reduction, one f64 atomic ----
#pragma unroll
    for (int off = 32; off > 0; off >>= 1)
        lsum += __shfl_down(lsum, off);
    if ((tid & 63) == 0) wsum[w] = lsum;
    __syncthreads();
    if (tid == 0)
        atomicAdd(acc, (double)(wsum[0] + wsum[1] + wsum[2] + wsum[3]));
}

extern "C" void kernel_launch(void* const* d_in, const int* in_sizes, int n_in,
                              void* d_out, int out_size, void* d_ws, size_t ws_size,
                              hipStream_t stream) {
    const float* preds = (const float*)d_in[0];
    const float* trues = (const float*)d_in[1];
    float* out = (float*)d_out;
    double* acc = (double*)d_ws;

    hipLaunchKernelGGL(zero_acc_kernel, dim3(1), dim3(64), 0, stream, acc);

    const int nblocks = 64 * 16;   // bid = (tx*2+h)*64 + v
    hipLaunchKernelGGL(ssim3d_kernel, dim3(nblocks), dim3(256), 0, stream,
                       preds, trues, acc);

    hipLaunchKernelGGL(finalize_kernel, dim3(1), dim3(64), 0, stream, acc, out);
}